// Round 17
// baseline (310.761 us; speedup 1.0000x reference)
//
#include <hip/hip_runtime.h>
#include <math.h>

// Problem constants
constexpr int Bc  = 32;
constexpr int Cc  = 1024;
constexpr int Mc  = 1024;
constexpr int Dc  = 512;
constexpr int DVc = 512;
constexpr int Rc  = 64;

typedef float f4 __attribute__((ext_vector_type(4)));

// ---------------------------------------------------------------------------
// Stage 1 of Ksum/Vsum with Tsum fused (r11 exact). 32 c-chunks of 32 rows,
// 256 threads, grid (32,32) = 1024 blocks. 8-deep batched T loads.
// ---------------------------------------------------------------------------
__global__ __launch_bounds__(256) void k_kv1(const float* __restrict__ T,
                                             const float* __restrict__ Wk,
                                             const float* __restrict__ Wv,
                                             float* __restrict__ pK,
                                             float* __restrict__ pV) {
    __shared__ float  ts[32];
    __shared__ float4 kp[2][128];
    __shared__ float4 vp[2][128];

    const int cs  = blockIdx.x;       // 0..31
    const int b   = blockIdx.y;
    const int c0  = cs * 32;
    const int tid = threadIdx.x;
    const int w   = tid >> 6, lane = tid & 63;  // 4 waves

    // ---- Phase 1: wave w sums rows [w*8, w*8+8); 2 rows (8 loads) per batch
    const float* Tb = T + ((long)b * Cc + c0 + w * 8) * Mc + lane * 4;
    float racc[8];
#pragma unroll
    for (int rp = 0; rp < 4; ++rp) {
        const float* r0 = Tb + (long)(2 * rp) * Mc;
        const float* r1 = r0 + Mc;
        float4 a[4], c[4];
#pragma unroll
        for (int k = 0; k < 4; ++k) a[k] = *(const float4*)&r0[k * 256];
#pragma unroll
        for (int k = 0; k < 4; ++k) c[k] = *(const float4*)&r1[k * 256];
        float s0 = 0.f, s1 = 0.f;
#pragma unroll
        for (int k = 0; k < 4; ++k) {
            s0 += (a[k].x + a[k].y) + (a[k].z + a[k].w);
            s1 += (c[k].x + c[k].y) + (c[k].z + c[k].w);
        }
        racc[2 * rp] = s0;
        racc[2 * rp + 1] = s1;
    }
#pragma unroll
    for (int off = 32; off; off >>= 1) {
#pragma unroll
        for (int r = 0; r < 8; ++r) racc[r] += __shfl_down(racc[r], off, 64);
    }
    if (lane == 0) {
#pragma unroll
        for (int r = 0; r < 8; ++r) ts[w * 8 + r] = racc[r];
    }
    __syncthreads();

    // ---- Phase 2: pK/pV partials, vectorized. tq = c-subgroup, tr = d/4 ----
    const int tq = tid >> 7, tr = tid & 127;  // tq 0..1
    const float4* Wk4 = (const float4*)(Wk + (long)c0 * Dc) + tr;
    const float4* Wv4 = (const float4*)(Wv + (long)c0 * DVc) + tr;
    float4 ka = {0.f, 0.f, 0.f, 0.f}, va = {0.f, 0.f, 0.f, 0.f};
#pragma unroll 4
    for (int j = 0; j < 16; ++j) {
        const int c = j * 2 + tq;
        const float t = ts[c];
        float4 wk = Wk4[(long)c * 128];
        float4 wv = Wv4[(long)c * 128];
        ka.x = fmaf(t, wk.x, ka.x); ka.y = fmaf(t, wk.y, ka.y);
        ka.z = fmaf(t, wk.z, ka.z); ka.w = fmaf(t, wk.w, ka.w);
        va.x = fmaf(t, wv.x, va.x); va.y = fmaf(t, wv.y, va.y);
        va.z = fmaf(t, wv.z, va.z); va.w = fmaf(t, wv.w, va.w);
    }
    kp[tq][tr] = ka;
    vp[tq][tr] = va;
    __syncthreads();

    const long base = ((long)b * 32 + cs) * 512;
    if (tid < 128) {
        float4 s0 = kp[0][tid], s1 = kp[1][tid];
        float4 s = {s0.x + s1.x, s0.y + s1.y, s0.z + s1.z, s0.w + s1.w};
        ((float4*)(pK + base))[tid] = s;
    } else {
        const int t2 = tid - 128;
        float4 s0 = vp[0][t2], s1 = vp[1][t2];
        float4 s = {s0.x + s1.x, s0.y + s1.y, s0.z + s1.z, s0.w + s1.w};
        ((float4*)(pV + base))[t2] = s;
    }
}

// ---------------------------------------------------------------------------
// Stage 2: Ksum/Vsum[b,d] = sum over 32 c-chunks (blocks 0..127; 32-deep
// batched loads), PLUS R_full row-sums (blocks 128..143). Grid 144 blocks.
// (r11 exact)
// ---------------------------------------------------------------------------
__global__ __launch_bounds__(256) void k_kv2r(const float* __restrict__ pK,
                                              const float* __restrict__ pV,
                                              float* __restrict__ Ksum,
                                              float* __restrict__ Vsum,
                                              const float* __restrict__ Rfull,
                                              float* __restrict__ rsum) {
    if (blockIdx.x < 128) {
        const int gid = blockIdx.x * 256 + threadIdx.x;  // 0..32767
        const int sel = gid >> 14;
        const int rem = gid & 16383;  // b*512 + d
        const float* p = (sel ? pV : pK) + (long)(rem >> 9) * 32 * 512 + (rem & 511);
        float v[32];
#pragma unroll
        for (int i = 0; i < 32; ++i) v[i] = p[i * 512];
        float s = 0.f;
#pragma unroll
        for (int i = 0; i < 32; ++i) s += v[i];
        (sel ? Vsum : Ksum)[rem] = s;
    } else {
        const int row  = (blockIdx.x - 128) * 4 + (threadIdx.x >> 6);  // 0..63
        const int lane = threadIdx.x & 63;
        const float* xr = Rfull + (long)row * 1024;
        float s = 0.f;
#pragma unroll
        for (int k = 0; k < 4; ++k) {
            float4 t = *(const float4*)&xr[k * 256 + lane * 4];
            s += (t.x + t.y) + (t.z + t.w);
        }
#pragma unroll
        for (int off = 32; off; off >>= 1) s += __shfl_down(s, off, 64);
        if (lane == 0) rsum[row] = s;
    }
}

// ---------------------------------------------------------------------------
// Merged middle kernel (r11 exact):
//  blocks [0, 8192):    wqk[b,c] = sum_d Wq[c,d]*Ksum[b,d]  (wave per (b,c))
//  blocks [8192, 8448): vw stage 1 — pVW[b,ds,c] partials over 64-d chunks
// ---------------------------------------------------------------------------
__global__ __launch_bounds__(256) void k_mid(const float* __restrict__ Wq,
                                             const float* __restrict__ Ksum,
                                             float* __restrict__ wqk,
                                             const float* __restrict__ Wout,
                                             const float* __restrict__ Vsum,
                                             float* __restrict__ pVW) {
    __shared__ float vs[64];
    if (blockIdx.x < 8192) {
        const int wid  = blockIdx.x * 4 + (threadIdx.x >> 6);  // b*1024 + c
        const int lane = threadIdx.x & 63;
        const float* wq = Wq + (long)(wid & 1023) * Dc;
        const float* ks = Ksum + (wid >> 10) * Dc;
        float s = 0.f;
#pragma unroll
        for (int k = 0; k < 4; ++k) {
            int d = k * 128 + lane * 2;
            float2 a = *(const float2*)&wq[d];
            float2 x = *(const float2*)&ks[d];
            s = fmaf(a.x, x.x, s);
            s = fmaf(a.y, x.y, s);
        }
#pragma unroll
        for (int off = 32; off; off >>= 1) s += __shfl_down(s, off, 64);
        if (lane == 0) wqk[wid] = s;
    } else {
        const int idx = blockIdx.x - 8192;
        const int ds  = idx & 7;
        const int b   = idx >> 3;
        const int d0  = ds * 64;
        const int tid = threadIdx.x;
        if (tid < 64) vs[tid] = Vsum[b * Dc + d0 + tid];
        __syncthreads();
        float a0 = 0.f, a1 = 0.f, a2 = 0.f, a3 = 0.f;
        const float* W0 = Wout + (long)d0 * Cc + tid;
#pragma unroll 4
        for (int d = 0; d < 64; ++d) {
            float v = vs[d];
            const float* wr = W0 + (long)d * Cc;
            a0 = fmaf(v, wr[0],   a0);
            a1 = fmaf(v, wr[256], a1);
            a2 = fmaf(v, wr[512], a2);
            a3 = fmaf(v, wr[768], a3);
        }
        const long base = ((long)b * 8 + ds) * 1024 + tid;
        pVW[base] = a0;  pVW[base + 256] = a1;
        pVW[base + 512] = a2;  pVW[base + 768] = a3;
    }
}

// ---------------------------------------------------------------------------
// Fused final (r11 exact geometry: m-tile 32, grid (32,32), 256 thr, pVW
// fold). SINGLE DELTA vs r11: stores are NORMAL instead of nontemporal —
// isolation experiment for r16's +21us regression (r16 bundled this with the
// k_mid2 fusion; this round separates them on the best-measured base).
// ---------------------------------------------------------------------------
__global__ __launch_bounds__(256) void k_final(const float* __restrict__ T,
                                               const float* __restrict__ wqk,
                                               const float* __restrict__ pVW,
                                               const float* __restrict__ rsum,
                                               float* __restrict__ Out,
                                               float scale) {
    __shared__ float rs[64];
    __shared__ float part[32][40];
    __shared__ float wsh[32];
    __shared__ float wql[Cc];
    __shared__ float vwl[Cc];

    const int b   = blockIdx.y;
    const int m0  = blockIdx.x * 32;
    const int tid = threadIdx.x;
    const int il  = tid & 7;    // m quarter (8 x 4 floats = 32 m)
    const int cs  = tid >> 3;   // 0..31

    // stage wqk[b,:] (256 threads x float4 = 1024 floats)
    ((float4*)wql)[tid] = ((const float4*)(wqk + b * Cc))[tid];
    // vw stage 2 folded: vwl[c] = sum_{j<8} pVW[b,j,c]
#pragma unroll
    for (int c = tid; c < Cc; c += 256) {
        const float* p = pVW + (long)b * 8 * 1024 + c;
        float v[8];
#pragma unroll
        for (int j = 0; j < 8; ++j) v[j] = p[j * 1024];
        float s = 0.f;
#pragma unroll
        for (int j = 0; j < 8; ++j) s += v[j];
        vwl[c] = s;
    }
    if (tid < 64) rs[tid] = rsum[tid];
    __syncthreads();

    const float* Tbm = T + (long)b * Cc * Mc + m0 + il * 4;
    float4 acc = make_float4(0.f, 0.f, 0.f, 0.f);
#pragma unroll
    for (int cb = 0; cb < 4; ++cb) {
        float4 t[8];
#pragma unroll
        for (int u = 0; u < 8; ++u)
            t[u] = *(const float4*)&Tbm[(long)(cs + (cb * 8 + u) * 32) * Mc];
#pragma unroll
        for (int u = 0; u < 8; ++u) {
            const float wc = wql[cs + (cb * 8 + u) * 32];
            acc.x = fmaf(t[u].x, wc, acc.x);
            acc.y = fmaf(t[u].y, wc, acc.y);
            acc.z = fmaf(t[u].z, wc, acc.z);
            acc.w = fmaf(t[u].w, wc, acc.w);
        }
    }
    *(float4*)&part[cs][il * 4] = acc;
    __syncthreads();

    if (tid < 32) {
        const int i = tid;
        float q = 0.f;
#pragma unroll
        for (int k = 0; k < 32; ++k) q += part[k][i];
        q *= scale;
        float mx = -1e30f;
#pragma unroll
        for (int r = 0; r < 64; ++r) mx = fmaxf(mx, q * rs[r]);
        float se = 0.f, sw = 0.f;
#pragma unroll
        for (int r = 0; r < 64; ++r) {
            float e = __expf(q * rs[r] - mx);
            se += e;
            sw = fmaf(e, rs[r], sw);
        }
        wsh[i] = sw / se;
    }
    __syncthreads();

    float* Ob = Out + (long)b * Cc * Mc + m0 + il * 4;
    float4 w4 = *(const float4*)&wsh[il * 4];
#pragma unroll 4
    for (int c = cs; c < Cc; c += 32) {
        float v = vwl[c];
        *(float4*)&Ob[(long)c * Mc] =
            make_float4(w4.x * v, w4.y * v, w4.z * v, w4.w * v);
    }
}

extern "C" void kernel_launch(void* const* d_in, const int* in_sizes, int n_in,
                              void* d_out, int out_size, void* d_ws, size_t ws_size,
                              hipStream_t stream) {
    const float* T     = (const float*)d_in[0];  // (B,C,M)
    const float* Wq    = (const float*)d_in[1];  // (C,D)
    const float* Wk    = (const float*)d_in[2];  // (C,D)
    const float* Wv    = (const float*)d_in[3];  // (C,DV)
    const float* Wout  = (const float*)d_in[4];  // (DV,C)
    const float* Rfull = (const float*)d_in[5];  // (R,M)
    float* Out = (float*)d_out;

    float* ws   = (float*)d_ws;
    float* rsum = ws;                  // 64
    float* Ksum = rsum + Rc;           // 16384
    float* Vsum = Ksum + Bc * Dc;      // 16384
    float* wqk  = Vsum + Bc * DVc;     // 32768
    float* vw   = wqk + Bc * Cc;       // 32768 (unused, layout kept)
    float* pK   = vw + Bc * Cc;        // 32*32*512 = 524288
    float* pV   = pK + 524288;         // 524288
    float* pVW  = pV + 524288;         // 262144

    // 1) kv stage 1 (fused Tsum): reads all of T once. 1024 blocks.
    k_kv1<<<dim3(32, Bc), 256, 0, stream>>>(T, Wk, Wv, pK, pV);
    // 2) kv stage 2 (32 chunks) + rsum folded in
    k_kv2r<<<144, 256, 0, stream>>>(pK, pV, Ksum, Vsum, Rfull, rsum);
    // 3) merged wqk + vw stage 1
    k_mid<<<8448, 256, 0, stream>>>(Wq, Ksum, wqk, Wout, Vsum, pVW);
    // 4) fused scores/softmax/output (normal stores — the isolated delta)
    const float scale = 1.0f / sqrtf((float)Dc);
    k_final<<<dim3(32, Bc), 256, 0, stream>>>(T, wqk, pVW, rsum, Out, scale);
}

// Round 18
// 282.273 us; speedup vs baseline: 1.1009x; 1.1009x over previous
//
#include <hip/hip_runtime.h>
#include <math.h>

// Problem constants
constexpr int Bc  = 32;
constexpr int Cc  = 1024;
constexpr int Mc  = 1024;
constexpr int Dc  = 512;
constexpr int DVc = 512;
constexpr int Rc  = 64;

typedef float f4 __attribute__((ext_vector_type(4)));

// ---------------------------------------------------------------------------
// Stage 1 of Ksum/Vsum with Tsum fused. 32 c-chunks of 32 rows, 256 threads,
// grid (32,32) = 1024 blocks. 8-deep batched T loads.
// ---------------------------------------------------------------------------
__global__ __launch_bounds__(256) void k_kv1(const float* __restrict__ T,
                                             const float* __restrict__ Wk,
                                             const float* __restrict__ Wv,
                                             float* __restrict__ pK,
                                             float* __restrict__ pV) {
    __shared__ float  ts[32];
    __shared__ float4 kp[2][128];
    __shared__ float4 vp[2][128];

    const int cs  = blockIdx.x;       // 0..31
    const int b   = blockIdx.y;
    const int c0  = cs * 32;
    const int tid = threadIdx.x;
    const int w   = tid >> 6, lane = tid & 63;  // 4 waves

    // ---- Phase 1: wave w sums rows [w*8, w*8+8); 2 rows (8 loads) per batch
    const float* Tb = T + ((long)b * Cc + c0 + w * 8) * Mc + lane * 4;
    float racc[8];
#pragma unroll
    for (int rp = 0; rp < 4; ++rp) {
        const float* r0 = Tb + (long)(2 * rp) * Mc;
        const float* r1 = r0 + Mc;
        float4 a[4], c[4];
#pragma unroll
        for (int k = 0; k < 4; ++k) a[k] = *(const float4*)&r0[k * 256];
#pragma unroll
        for (int k = 0; k < 4; ++k) c[k] = *(const float4*)&r1[k * 256];
        float s0 = 0.f, s1 = 0.f;
#pragma unroll
        for (int k = 0; k < 4; ++k) {
            s0 += (a[k].x + a[k].y) + (a[k].z + a[k].w);
            s1 += (c[k].x + c[k].y) + (c[k].z + c[k].w);
        }
        racc[2 * rp] = s0;
        racc[2 * rp + 1] = s1;
    }
#pragma unroll
    for (int off = 32; off; off >>= 1) {
#pragma unroll
        for (int r = 0; r < 8; ++r) racc[r] += __shfl_down(racc[r], off, 64);
    }
    if (lane == 0) {
#pragma unroll
        for (int r = 0; r < 8; ++r) ts[w * 8 + r] = racc[r];
    }
    __syncthreads();

    // ---- Phase 2: pK/pV partials, vectorized. tq = c-subgroup, tr = d/4 ----
    const int tq = tid >> 7, tr = tid & 127;  // tq 0..1
    const float4* Wk4 = (const float4*)(Wk + (long)c0 * Dc) + tr;
    const float4* Wv4 = (const float4*)(Wv + (long)c0 * DVc) + tr;
    float4 ka = {0.f, 0.f, 0.f, 0.f}, va = {0.f, 0.f, 0.f, 0.f};
#pragma unroll 4
    for (int j = 0; j < 16; ++j) {
        const int c = j * 2 + tq;
        const float t = ts[c];
        float4 wk = Wk4[(long)c * 128];
        float4 wv = Wv4[(long)c * 128];
        ka.x = fmaf(t, wk.x, ka.x); ka.y = fmaf(t, wk.y, ka.y);
        ka.z = fmaf(t, wk.z, ka.z); ka.w = fmaf(t, wk.w, ka.w);
        va.x = fmaf(t, wv.x, va.x); va.y = fmaf(t, wv.y, va.y);
        va.z = fmaf(t, wv.z, va.z); va.w = fmaf(t, wv.w, va.w);
    }
    kp[tq][tr] = ka;
    vp[tq][tr] = va;
    __syncthreads();

    const long base = ((long)b * 32 + cs) * 512;
    if (tid < 128) {
        float4 s0 = kp[0][tid], s1 = kp[1][tid];
        float4 s = {s0.x + s1.x, s0.y + s1.y, s0.z + s1.z, s0.w + s1.w};
        ((float4*)(pK + base))[tid] = s;
    } else {
        const int t2 = tid - 128;
        float4 s0 = vp[0][t2], s1 = vp[1][t2];
        float4 s = {s0.x + s1.x, s0.y + s1.y, s0.z + s1.z, s0.w + s1.w};
        ((float4*)(pV + base))[t2] = s;
    }
}

// ---------------------------------------------------------------------------
// Fused middle kernel, grid (9, 32) = 288 blocks, 256 threads (r16 exact;
// measured -3.7us vs the k_kv2r+k_mid split under identical store types).
//  j<8 blocks: Ksum/Vsum[b] reduced into LDS from L2-resident pK/pV, then
//    wqk[b, j*128..+128] and vw[b, j*128..+128] directly.
//  j==8 blocks: rsum rows 2b, 2b+1.
// ---------------------------------------------------------------------------
__global__ __launch_bounds__(256) void k_mid2(const float* __restrict__ pK,
                                              const float* __restrict__ pV,
                                              const float* __restrict__ Wq,
                                              const float* __restrict__ Wout,
                                              const float* __restrict__ Rfull,
                                              float* __restrict__ wqk,
                                              float* __restrict__ vw,
                                              float* __restrict__ rsum) {
    __shared__ float Ks[512];
    __shared__ float Vs[512];
    __shared__ float pvw[256];

    const int j   = blockIdx.x;   // 0..8
    const int b   = blockIdx.y;
    const int tid = threadIdx.x;
    const int w   = tid >> 6, lane = tid & 63;

    if (j == 8) {  // rsum rows 2b, 2b+1
        if (w < 2) {
            const int row = 2 * b + w;
            const float* xr = Rfull + (long)row * 1024;
            float s = 0.f;
#pragma unroll
            for (int k = 0; k < 4; ++k) {
                float4 t = *(const float4*)&xr[k * 256 + lane * 4];
                s += (t.x + t.y) + (t.z + t.w);
            }
#pragma unroll
            for (int off = 32; off; off >>= 1) s += __shfl_down(s, off, 64);
            if (lane == 0) rsum[row] = s;
        }
        return;
    }

    // ---- Phase 1: Ksum/Vsum[b] into LDS (pK/pV are 2 MB each, L2-hot) ----
    {
        const float* pKb = pK + (long)b * 32 * 512;
        const float* pVb = pV + (long)b * 32 * 512;
        float v[32];
#pragma unroll
        for (int i = 0; i < 32; ++i) v[i] = pKb[i * 512 + tid];
        float s = 0.f;
#pragma unroll
        for (int i = 0; i < 32; ++i) s += v[i];
        Ks[tid] = s;
#pragma unroll
        for (int i = 0; i < 32; ++i) v[i] = pKb[i * 512 + tid + 256];
        s = 0.f;
#pragma unroll
        for (int i = 0; i < 32; ++i) s += v[i];
        Ks[tid + 256] = s;
#pragma unroll
        for (int i = 0; i < 32; ++i) v[i] = pVb[i * 512 + tid];
        s = 0.f;
#pragma unroll
        for (int i = 0; i < 32; ++i) s += v[i];
        Vs[tid] = s;
#pragma unroll
        for (int i = 0; i < 32; ++i) v[i] = pVb[i * 512 + tid + 256];
        s = 0.f;
#pragma unroll
        for (int i = 0; i < 32; ++i) s += v[i];
        Vs[tid + 256] = s;
    }
    __syncthreads();

    const int c0 = j * 128;

    // ---- Phase 2: wqk. Wave w owns c in [c0+w*32, +32), 8 c's in flight ----
    {
        float myKs[8];
#pragma unroll
        for (int k = 0; k < 8; ++k) myKs[k] = Ks[lane + k * 64];
        const int cbase = c0 + w * 32;
#pragma unroll
        for (int bt = 0; bt < 4; ++bt) {
            float p[8];
#pragma unroll
            for (int u = 0; u < 8; ++u) {
                const float* wqr = Wq + (long)(cbase + bt * 8 + u) * Dc + lane;
                float acc = 0.f;
#pragma unroll
                for (int k = 0; k < 8; ++k) acc = fmaf(wqr[k * 64], myKs[k], acc);
                p[u] = acc;
            }
#pragma unroll
            for (int off = 32; off; off >>= 1) {
#pragma unroll
                for (int u = 0; u < 8; ++u) p[u] += __shfl_down(p[u], off, 64);
            }
            if (lane == 0) {
#pragma unroll
                for (int u = 0; u < 8; ++u) wqk[b * Cc + cbase + bt * 8 + u] = p[u];
            }
        }
    }

    // ---- Phase 3: vw. thread = (c index 0..127, d-half); 8-deep batches ----
    {
        const int ci = tid & 127, h = tid >> 7;
        const float* W0 = Wout + (long)(h * 256) * Cc + c0 + ci;
        float acc = 0.f;
#pragma unroll 4
        for (int d0 = 0; d0 < 256; d0 += 8) {
            float w8[8];
#pragma unroll
            for (int q = 0; q < 8; ++q) w8[q] = W0[(long)(d0 + q) * Cc];
#pragma unroll
            for (int q = 0; q < 8; ++q) acc = fmaf(Vs[h * 256 + d0 + q], w8[q], acc);
        }
        pvw[tid] = acc;
        __syncthreads();
        if (tid < 128) vw[b * Cc + c0 + tid] = pvw[tid] + pvw[tid + 128];
    }
}

// ---------------------------------------------------------------------------
// Fused final (m-tile 32, grid (32,32), 256 thr, vwl from vw). SINGLE DELTA
// vs r16: stores restored to NONTEMPORAL. r17 isolated NT->normal as +25us
// (read-for-ownership fetches each Out line before overwrite = +134MB read
// traffic; NT full-line stores skip the RFO). Recombining the two measured-
// good pieces: NT stores (-25) + k_mid2 fusion (-3.7).
// ---------------------------------------------------------------------------
__global__ __launch_bounds__(256) void k_final(const float* __restrict__ T,
                                               const float* __restrict__ wqk,
                                               const float* __restrict__ vw,
                                               const float* __restrict__ rsum,
                                               float* __restrict__ Out,
                                               float scale) {
    __shared__ float rs[64];
    __shared__ float part[32][40];
    __shared__ float wsh[32];
    __shared__ float wql[Cc];
    __shared__ float vwl[Cc];

    const int b   = blockIdx.y;
    const int m0  = blockIdx.x * 32;
    const int tid = threadIdx.x;
    const int il  = tid & 7;    // m quarter (8 x 4 floats = 32 m)
    const int cs  = tid >> 3;   // 0..31

    ((float4*)wql)[tid] = ((const float4*)(wqk + b * Cc))[tid];
    ((float4*)vwl)[tid] = ((const float4*)(vw  + b * Cc))[tid];
    if (tid < 64) rs[tid] = rsum[tid];
    __syncthreads();

    const float* Tbm = T + (long)b * Cc * Mc + m0 + il * 4;
    float4 acc = make_float4(0.f, 0.f, 0.f, 0.f);
#pragma unroll
    for (int cb = 0; cb < 4; ++cb) {
        float4 t[8];
#pragma unroll
        for (int u = 0; u < 8; ++u)
            t[u] = *(const float4*)&Tbm[(long)(cs + (cb * 8 + u) * 32) * Mc];
#pragma unroll
        for (int u = 0; u < 8; ++u) {
            const float wc = wql[cs + (cb * 8 + u) * 32];
            acc.x = fmaf(t[u].x, wc, acc.x);
            acc.y = fmaf(t[u].y, wc, acc.y);
            acc.z = fmaf(t[u].z, wc, acc.z);
            acc.w = fmaf(t[u].w, wc, acc.w);
        }
    }
    *(float4*)&part[cs][il * 4] = acc;
    __syncthreads();

    if (tid < 32) {
        const int i = tid;
        float q = 0.f;
#pragma unroll
        for (int k = 0; k < 32; ++k) q += part[k][i];
        q *= scale;
        float mx = -1e30f;
#pragma unroll
        for (int r = 0; r < 64; ++r) mx = fmaxf(mx, q * rs[r]);
        float se = 0.f, sw = 0.f;
#pragma unroll
        for (int r = 0; r < 64; ++r) {
            float e = __expf(q * rs[r] - mx);
            se += e;
            sw = fmaf(e, rs[r], sw);
        }
        wsh[i] = sw / se;
    }
    __syncthreads();

    float* Ob = Out + (long)b * Cc * Mc + m0 + il * 4;
    float4 w4 = *(const float4*)&wsh[il * 4];
#pragma unroll 4
    for (int c = cs; c < Cc; c += 32) {
        float v = vwl[c];
        f4 o = {w4.x * v, w4.y * v, w4.z * v, w4.w * v};
        __builtin_nontemporal_store(o, (f4*)&Ob[(long)c * Mc]);
    }
}

extern "C" void kernel_launch(void* const* d_in, const int* in_sizes, int n_in,
                              void* d_out, int out_size, void* d_ws, size_t ws_size,
                              hipStream_t stream) {
    const float* T     = (const float*)d_in[0];  // (B,C,M)
    const float* Wq    = (const float*)d_in[1];  // (C,D)
    const float* Wk    = (const float*)d_in[2];  // (C,D)
    const float* Wv    = (const float*)d_in[3];  // (C,DV)
    const float* Wout  = (const float*)d_in[4];  // (DV,C)
    const float* Rfull = (const float*)d_in[5];  // (R,M)
    float* Out = (float*)d_out;

    float* ws   = (float*)d_ws;
    float* rsum = ws;                  // 64
    float* wqk  = rsum + Rc + 32768;   // (gap keeps old layout offsets)
    float* vw   = wqk + Bc * Cc;       // 32768
    float* pK   = vw + Bc * Cc;        // 32*32*512 = 524288
    float* pV   = pK + 524288;         // 524288

    // 1) kv stage 1 (fused Tsum): reads all of T once. 1024 blocks.
    k_kv1<<<dim3(32, Bc), 256, 0, stream>>>(T, Wk, Wv, pK, pV);
    // 2) fused middles: Ksum/Vsum reduce + wqk + vw + rsum. 288 blocks.
    k_mid2<<<dim3(9, Bc), 256, 0, stream>>>(pK, pV, Wq, Wout, Rfull, wqk, vw, rsum);
    // 3) fused scores/softmax/output (NT stores). 1024 blocks.
    const float scale = 1.0f / sqrtf((float)Dc);
    k_final<<<dim3(32, Bc), 256, 0, stream>>>(T, wqk, vw, rsum, Out, scale);
}